// Round 16
// baseline (279.993 us; speedup 1.0000x reference)
//
#include <hip/hip_runtime.h>
#include <math.h>

#define N_NODES 100000
#define N_EDGES 1600000
#define N_GRAPHS 64
#define HID 64
#define LN_EPS 1e-5f
#define ECAP 32                           // per-node edge-slot capacity
#define OVF_CAP 4096                      // expected ~20 used (P(deg>32)~1e-4)
#define KA_BLOCKS 1024                    // 128 blocks/XCD (2x R15's TLP)
#define KD_BLOCKS 2048
#define KD_WAVES (KD_BLOCKS * 4)          // 8192 waves (settled, R13)
#define KD_CHUNK ((N_NODES + KD_WAVES - 1) / KD_WAVES)  // 13 contiguous nodes/wave

__device__ __forceinline__ float waveReduceSum(float v) {
#pragma unroll
    for (int off = 32; off > 0; off >>= 1)
        v += __shfl_xor(v, off, 64);
    return v;
}

__device__ __forceinline__ float groupReduceSum16(float v) {
#pragma unroll
    for (int off = 8; off > 0; off >>= 1)
        v += __shfl_xor(v, off, 64);
    return v;
}

__device__ __forceinline__ unsigned rne_bf16(float f) {
    unsigned u = __float_as_uint(f);
    return (u + 0x7fffu + ((u >> 16) & 1u)) >> 16;
}

// K0: per-node transforms (xl, xr packed bf16) + all workspace init.
__global__ __launch_bounds__(256) void k0_transform(
    const float* __restrict__ x,
    const float* __restrict__ Wl, const float* __restrict__ bl,
    const float* __restrict__ Wr, const float* __restrict__ br,
    uint2* __restrict__ xlh, uint2* __restrict__ xrh,
    int* __restrict__ deg, int* __restrict__ ovf_cnt,
    float* __restrict__ gsum, float* __restrict__ gcnt,
    double* __restrict__ stats) {
    if (blockIdx.x == 0) {
        for (int i = threadIdx.x; i < N_GRAPHS * HID; i += blockDim.x) gsum[i] = 0.f;
        if (threadIdx.x < N_GRAPHS) gcnt[threadIdx.x] = 0.f;
        if (threadIdx.x < 2) stats[threadIdx.x] = 0.0;
        if (threadIdx.x == 0) *ovf_cnt = 0;
    }
    int t = blockIdx.x * blockDim.x + threadIdx.x;
    int n = t >> 4;
    int cg = t & 15;
    if (n >= N_NODES) return;
    float4 xv = ((const float4*)x)[n];
    float4 w0 = ((const float4*)Wl)[0 * 16 + cg];
    float4 w1 = ((const float4*)Wl)[1 * 16 + cg];
    float4 w2 = ((const float4*)Wl)[2 * 16 + cg];
    float4 w3 = ((const float4*)Wl)[3 * 16 + cg];
    float4 bv = ((const float4*)bl)[cg];
    float4 vl;
    vl.x = bv.x + xv.x * w0.x + xv.y * w1.x + xv.z * w2.x + xv.w * w3.x;
    vl.y = bv.y + xv.x * w0.y + xv.y * w1.y + xv.z * w2.y + xv.w * w3.y;
    vl.z = bv.z + xv.x * w0.z + xv.y * w1.z + xv.z * w2.z + xv.w * w3.z;
    vl.w = bv.w + xv.x * w0.w + xv.y * w1.w + xv.z * w2.w + xv.w * w3.w;
    w0 = ((const float4*)Wr)[0 * 16 + cg];
    w1 = ((const float4*)Wr)[1 * 16 + cg];
    w2 = ((const float4*)Wr)[2 * 16 + cg];
    w3 = ((const float4*)Wr)[3 * 16 + cg];
    bv = ((const float4*)br)[cg];
    float4 vr;
    vr.x = bv.x + xv.x * w0.x + xv.y * w1.x + xv.z * w2.x + xv.w * w3.x;
    vr.y = bv.y + xv.x * w0.y + xv.y * w1.y + xv.z * w2.y + xv.w * w3.y;
    vr.z = bv.z + xv.x * w0.z + xv.y * w1.z + xv.z * w2.z + xv.w * w3.z;
    vr.w = bv.w + xv.x * w0.w + xv.y * w1.w + xv.z * w2.w + xv.w * w3.w;
    uint2 p;
    p.x = rne_bf16(vl.x) | (rne_bf16(vl.y) << 16);
    p.y = rne_bf16(vl.z) | (rne_bf16(vl.w) << 16);
    xlh[n * 16 + cg] = p;
    uint2 r;
    r.x = rne_bf16(vr.x) | (rne_bf16(vr.y) << 16);
    r.y = rne_bf16(vr.z) | (rne_bf16(vr.w) << 16);
    xrh[n * 16 + cg] = r;
    if (cg == 0) deg[n] = 0;
}

// KA: direct-placement histogram (replaces scan+place pipeline; R15 win).
// v2: 1024 blocks (2x TLP) and explicit MLP — all 4 independent atomicAdds
// issued before any dependent store, so the 4 L2 round-trips overlap.
// XCD-partitioned by dst (R6): esrc slice = 1.6MB/XCD -> writes merge in L2.
__global__ __launch_bounds__(256) void ka_direct(const int* __restrict__ ei,
                                                 int* __restrict__ deg,
                                                 int* __restrict__ esrc,
                                                 int2* __restrict__ ovf,
                                                 int* __restrict__ ovf_cnt) {
    int xcd = blockIdx.x & 7;
    int sub = blockIdx.x >> 3;                 // 0..127
    int lo = xcd * (N_NODES / 8);
    int hi = lo + (N_NODES / 8);
    int tid = sub * 256 + (int)threadIdx.x;    // 0..32767 within XCD group
    for (int q = tid; q < N_EDGES / 4; q += 128 * 256) {
        int4 d4 = ((const int4*)(ei + N_EDGES))[q];
        int4 s4 = ((const int4*)ei)[q];
        int d[4] = {d4.x, d4.y, d4.z, d4.w};
        int s[4] = {s4.x, s4.y, s4.z, s4.w};
        int r[4];
        bool own[4];
        // pass 1: issue all independent atomics (4 overlapping L2 round-trips)
#pragma unroll
        for (int k = 0; k < 4; ++k) {
            own[k] = (d[k] >= lo) && (d[k] < hi);
            r[k] = own[k] ? atomicAdd(&deg[d[k]], 1) : 0;
        }
        // pass 2: dependent stores
#pragma unroll
        for (int k = 0; k < 4; ++k) {
            if (own[k]) {
                if (r[k] < ECAP) {
                    esrc[d[k] * ECAP + r[k]] = s[k];
                } else {
                    int o = atomicAdd(ovf_cnt, 1);
                    ovf[o] = make_int2(d[k], s[k]);
                }
            }
        }
    }
}

// KD: fused node aggregation + LN stats + graph pooling. SETTLED body
// (4 slots x 16 lanes, uint2, VGPR 32, 2048 blocks — R7/R9/R12/R13 lessons).
// Padded layout: base = n*ECAP, count = deg[n]; deg>ECAP scans overflow list.
__global__ __launch_bounds__(256, 8) void kd_node_agg(
    const int* __restrict__ deg, const int* __restrict__ esrc,
    const int2* __restrict__ ovf, const int* __restrict__ ovf_cnt,
    const uint2* __restrict__ xlh, const uint2* __restrict__ xrh,
    const float* __restrict__ att, const float* __restrict__ cb,
    const int* __restrict__ batch,
    float* __restrict__ gsum, float* __restrict__ gcnt,
    double* __restrict__ stats) {
    __shared__ float sS[4], sQ[4];
    int w = threadIdx.x >> 6;             // wave-in-block 0..3
    int lane = threadIdx.x & 63;
    int slot = lane >> 4;                 // 0..3: edge slot
    int cg = lane & 15;                   // channel group (4 ch)
    int wid = blockIdx.x * 4 + w;
    int n0 = wid * KD_CHUNK;
    int n1 = min(n0 + KD_CHUNK, N_NODES);

    float4 av = ((const float4*)att)[cg];
    float4 cv = ((const float4*)cb)[cg];

    float lsum = 0.f, lsq = 0.f;
    float gacc0 = 0.f, gacc1 = 0.f, gacc2 = 0.f, gacc3 = 0.f;
    float runcnt = 0.f;
    int cur_g = -1;

    for (int n = n0; n < n1; ++n) {
        int dtot = deg[n];
        int dpk = min(dtot, ECAP);
        int base = n * ECAP;
        uint2 rp = xrh[n * 16 + cg];
        float4 xr;
        xr.x = __uint_as_float(rp.x << 16);
        xr.y = __uint_as_float(rp.x & 0xffff0000u);
        xr.z = __uint_as_float(rp.y << 16);
        xr.w = __uint_as_float(rp.y & 0xffff0000u);
        float num0 = 0.f, num1 = 0.f, num2 = 0.f, num3 = 0.f, den = 0.f;
        int j = slot;
        uint2 p = make_uint2(0, 0);
        if (j < dpk) p = xlh[esrc[base + j] * 16 + cg];
        for (int j0 = 0; j0 < dpk; j0 += 4) {
            uint2 pc = p;
            bool vc = (j0 + slot) < dpk;
            int jn = j0 + 4 + slot;
            if (jn < dpk) p = xlh[esrc[base + jn] * 16 + cg];
            float f0 = __uint_as_float(pc.x << 16);
            float f1 = __uint_as_float(pc.x & 0xffff0000u);
            float f2 = __uint_as_float(pc.y << 16);
            float f3 = __uint_as_float(pc.y & 0xffff0000u);
            float h0 = f0 + xr.x, h1 = f1 + xr.y, h2 = f2 + xr.z, h3 = f3 + xr.w;
            float l0 = fmaxf(h0, 0.f) + 0.2f * fminf(h0, 0.f);
            float l1 = fmaxf(h1, 0.f) + 0.2f * fminf(h1, 0.f);
            float l2 = fmaxf(h2, 0.f) + 0.2f * fminf(h2, 0.f);
            float l3 = fmaxf(h3, 0.f) + 0.2f * fminf(h3, 0.f);
            float part = l0 * av.x + l1 * av.y + l2 * av.z + l3 * av.w;
            float e = groupReduceSum16(part);   // within-slot 16-lane reduce
            float ex = vc ? __expf(e) : 0.f;
            den += ex;
            num0 += ex * f0; num1 += ex * f1; num2 += ex * f2; num3 += ex * f3;
        }
        if (dtot > ECAP) {   // overflow fallback: scan tiny (dst,src) list
            int m = *ovf_cnt;
            for (int t = 0; t < m; ++t) {
                int2 od = ovf[t];
                if (od.x != n) continue;
                uint2 pc = make_uint2(0, 0);
                if (slot == 0) pc = xlh[od.y * 16 + cg];
                float f0 = __uint_as_float(pc.x << 16);
                float f1 = __uint_as_float(pc.x & 0xffff0000u);
                float f2 = __uint_as_float(pc.y << 16);
                float f3 = __uint_as_float(pc.y & 0xffff0000u);
                float h0 = f0 + xr.x, h1 = f1 + xr.y, h2 = f2 + xr.z, h3 = f3 + xr.w;
                float l0 = fmaxf(h0, 0.f) + 0.2f * fminf(h0, 0.f);
                float l1 = fmaxf(h1, 0.f) + 0.2f * fminf(h1, 0.f);
                float l2 = fmaxf(h2, 0.f) + 0.2f * fminf(h2, 0.f);
                float l3 = fmaxf(h3, 0.f) + 0.2f * fminf(h3, 0.f);
                float part = l0 * av.x + l1 * av.y + l2 * av.z + l3 * av.w;
                float e = groupReduceSum16(part);
                float ex = (slot == 0) ? __expf(e) : 0.f;
                den += ex;
                num0 += ex * f0; num1 += ex * f1; num2 += ex * f2; num3 += ex * f3;
            }
        }
#pragma unroll
        for (int off = 16; off <= 32; off <<= 1) {
            num0 += __shfl_xor(num0, off, 64);
            num1 += __shfl_xor(num1, off, 64);
            num2 += __shfl_xor(num2, off, 64);
            num3 += __shfl_xor(num3, off, 64);
            den += __shfl_xor(den, off, 64);
        }
        float inv = (den > 0.f) ? (1.f / den) : 0.f;
        float v0 = fmaxf(num0 * inv + cv.x, 0.f);
        float v1 = fmaxf(num1 * inv + cv.y, 0.f);
        float v2 = fmaxf(num2 * inv + cv.z, 0.f);
        float v3 = fmaxf(num3 * inv + cv.w, 0.f);
        if (slot == 0) {   // values replicated across slots; count once
            lsum += v0 + v1 + v2 + v3;
            lsq += v0 * v0 + v1 * v1 + v2 * v2 + v3 * v3;
            int g = batch[n];
            if (g != cur_g) {
                if (cur_g >= 0) {
                    unsafeAtomicAdd(&gsum[cur_g * HID + cg * 4 + 0], gacc0);
                    unsafeAtomicAdd(&gsum[cur_g * HID + cg * 4 + 1], gacc1);
                    unsafeAtomicAdd(&gsum[cur_g * HID + cg * 4 + 2], gacc2);
                    unsafeAtomicAdd(&gsum[cur_g * HID + cg * 4 + 3], gacc3);
                    if (cg == 0) unsafeAtomicAdd(&gcnt[cur_g], runcnt);
                }
                cur_g = g;
                gacc0 = gacc1 = gacc2 = gacc3 = 0.f;
                runcnt = 0.f;
            }
            gacc0 += v0; gacc1 += v1; gacc2 += v2; gacc3 += v3;
            runcnt += 1.f;
        }
    }
    if (cur_g >= 0) {   // only slot-0 lanes have cur_g >= 0
        unsafeAtomicAdd(&gsum[cur_g * HID + cg * 4 + 0], gacc0);
        unsafeAtomicAdd(&gsum[cur_g * HID + cg * 4 + 1], gacc1);
        unsafeAtomicAdd(&gsum[cur_g * HID + cg * 4 + 2], gacc2);
        unsafeAtomicAdd(&gsum[cur_g * HID + cg * 4 + 3], gacc3);
        if (cg == 0) unsafeAtomicAdd(&gcnt[cur_g], runcnt);
    }
    lsum = groupReduceSum16(lsum);
    lsq = groupReduceSum16(lsq);
    if (lane == 0) { sS[w] = lsum; sQ[w] = lsq; }
    __syncthreads();
    if (threadIdx.x == 0) {
        double ds = 0.0, dq = 0.0;
#pragma unroll
        for (int i = 0; i < 4; ++i) { ds += (double)sS[i]; dq += (double)sQ[i]; }
        unsafeAtomicAdd(&stats[0], ds);
        unsafeAtomicAdd(&stats[1], dq);
    }
}

// K4: per-graph head (separate launch; fence fusion costs 135us — R12).
__global__ __launch_bounds__(64) void k4_head(
    const float* __restrict__ gsum, const float* __restrict__ gcnt,
    const double* __restrict__ stats,
    const float* __restrict__ lnw, const float* __restrict__ lnb,
    const float* __restrict__ linw, const float* __restrict__ linb,
    float* __restrict__ y) {
    int g = blockIdx.x;
    int lane = threadIdx.x;
    double tot = (double)N_NODES * (double)HID;
    double mu = stats[0] / tot;
    double var = stats[1] / tot - mu * mu;
    float rs = rsqrtf((float)var + LN_EPS);
    float cnt = fmaxf(gcnt[g], 1.f);
    float pooled = (gsum[g * HID + lane] / cnt - (float)mu) * rs * lnw[lane] + lnb[lane];
    float t = waveReduceSum(pooled * linw[lane]);
    if (lane == 0) {
        float z = t + linb[0];
        y[g] = 1.f / (1.f + __expf(-z));
    }
}

extern "C" void kernel_launch(void* const* d_in, const int* in_sizes, int n_in,
                              void* d_out, int out_size, void* d_ws, size_t ws_size,
                              hipStream_t stream) {
    const float* x = (const float*)d_in[0];
    const int* ei = (const int*)d_in[1];
    const int* batch = (const int*)d_in[2];
    const float* Wl = (const float*)d_in[3];
    const float* bl = (const float*)d_in[4];
    const float* Wr = (const float*)d_in[5];
    const float* br = (const float*)d_in[6];
    const float* att = (const float*)d_in[7];
    const float* cb = (const float*)d_in[8];
    const float* lnw = (const float*)d_in[9];
    const float* lnb = (const float*)d_in[10];
    const float* linw = (const float*)d_in[11];
    const float* linb = (const float*)d_in[12];
    float* y = (float*)d_out;

    char* ws = (char*)d_ws;
    uint2* xlh = (uint2*)ws;                                     // N*16 uint2 (12.8MB)
    uint2* xrh = (uint2*)(ws + (size_t)N_NODES * 128);           // N*16 uint2 (12.8MB)
    float* gsum = (float*)(ws + (size_t)N_NODES * 256);          // 64*64
    float* gcnt = gsum + N_GRAPHS * HID;                         // 64
    double* stats = (double*)(gcnt + N_GRAPHS);                  // 2 doubles
    int* deg = (int*)(stats + 2);                                // N
    int* ovf_cnt = deg + N_NODES;                                // 1 (+1 pad)
    int2* ovf = (int2*)(ovf_cnt + 2);                            // OVF_CAP int2
    int* esrc = (int*)(ovf + OVF_CAP);                           // N*ECAP (12.8MB)

    k0_transform<<<(N_NODES * 16 + 255) / 256, 256, 0, stream>>>(
        x, Wl, bl, Wr, br, xlh, xrh, deg, ovf_cnt, gsum, gcnt, stats);
    ka_direct<<<KA_BLOCKS, 256, 0, stream>>>(ei, deg, esrc, ovf, ovf_cnt);
    kd_node_agg<<<KD_BLOCKS, 256, 0, stream>>>(
        deg, esrc, ovf, ovf_cnt, xlh, xrh, att, cb, batch, gsum, gcnt, stats);
    k4_head<<<N_GRAPHS, 64, 0, stream>>>(gsum, gcnt, stats, lnw, lnb, linw, linb, y);
}

// Round 17
// 273.854 us; speedup vs baseline: 1.0224x; 1.0224x over previous
//
#include <hip/hip_runtime.h>
#include <math.h>

#define N_NODES 100000
#define N_EDGES 1600000
#define N_GRAPHS 64
#define HID 64
#define LN_EPS 1e-5f
#define ECAP 32                           // per-node edge-slot capacity
#define OVF_CAP 4096                      // expected ~20 used (P(deg>32)~1e-4)
#define KA_BLOCKS 1024                    // 128 blocks/XCD
#define KD_BLOCKS 2048
#define KD_WAVES (KD_BLOCKS * 4)          // 8192 waves (settled, R13)
#define KD_CHUNK ((N_NODES + KD_WAVES - 1) / KD_WAVES)  // 13 contiguous nodes/wave

__device__ __forceinline__ float waveReduceSum(float v) {
#pragma unroll
    for (int off = 32; off > 0; off >>= 1)
        v += __shfl_xor(v, off, 64);
    return v;
}

__device__ __forceinline__ float groupReduceSum16(float v) {
#pragma unroll
    for (int off = 8; off > 0; off >>= 1)
        v += __shfl_xor(v, off, 64);
    return v;
}

__device__ __forceinline__ unsigned rne_bf16(float f) {
    unsigned u = __float_as_uint(f);
    return (u + 0x7fffu + ((u >> 16) & 1u)) >> 16;
}

// Workgroup-scope atomic: executes at the issuing XCD's L2 (no memory-side
// fabric round-trip). CORRECT here only because of the XCD dst-partition:
// all writers of a given deg[d] live on one XCD, whose L2 serializes the
// RMWs; cross-kernel visibility comes from the L2 writeback at dispatch
// boundaries (the same mechanism the plain esrc stores already rely on).
__device__ __forceinline__ int l2AtomicAdd(int* p, int v) {
    return __hip_atomic_fetch_add(p, v, __ATOMIC_RELAXED,
                                  __HIP_MEMORY_SCOPE_WORKGROUP);
}

// K0: per-node transforms (xl, xr packed bf16) + all workspace init.
__global__ __launch_bounds__(256) void k0_transform(
    const float* __restrict__ x,
    const float* __restrict__ Wl, const float* __restrict__ bl,
    const float* __restrict__ Wr, const float* __restrict__ br,
    uint2* __restrict__ xlh, uint2* __restrict__ xrh,
    int* __restrict__ deg, int* __restrict__ ovf_cnt,
    float* __restrict__ gsum, float* __restrict__ gcnt,
    double* __restrict__ stats) {
    if (blockIdx.x == 0) {
        for (int i = threadIdx.x; i < N_GRAPHS * HID; i += blockDim.x) gsum[i] = 0.f;
        if (threadIdx.x < N_GRAPHS) gcnt[threadIdx.x] = 0.f;
        if (threadIdx.x < 2) stats[threadIdx.x] = 0.0;
        if (threadIdx.x == 0) *ovf_cnt = 0;
    }
    int t = blockIdx.x * blockDim.x + threadIdx.x;
    int n = t >> 4;
    int cg = t & 15;
    if (n >= N_NODES) return;
    float4 xv = ((const float4*)x)[n];
    float4 w0 = ((const float4*)Wl)[0 * 16 + cg];
    float4 w1 = ((const float4*)Wl)[1 * 16 + cg];
    float4 w2 = ((const float4*)Wl)[2 * 16 + cg];
    float4 w3 = ((const float4*)Wl)[3 * 16 + cg];
    float4 bv = ((const float4*)bl)[cg];
    float4 vl;
    vl.x = bv.x + xv.x * w0.x + xv.y * w1.x + xv.z * w2.x + xv.w * w3.x;
    vl.y = bv.y + xv.x * w0.y + xv.y * w1.y + xv.z * w2.y + xv.w * w3.y;
    vl.z = bv.z + xv.x * w0.z + xv.y * w1.z + xv.z * w2.z + xv.w * w3.z;
    vl.w = bv.w + xv.x * w0.w + xv.y * w1.w + xv.z * w2.w + xv.w * w3.w;
    w0 = ((const float4*)Wr)[0 * 16 + cg];
    w1 = ((const float4*)Wr)[1 * 16 + cg];
    w2 = ((const float4*)Wr)[2 * 16 + cg];
    w3 = ((const float4*)Wr)[3 * 16 + cg];
    bv = ((const float4*)br)[cg];
    float4 vr;
    vr.x = bv.x + xv.x * w0.x + xv.y * w1.x + xv.z * w2.x + xv.w * w3.x;
    vr.y = bv.y + xv.x * w0.y + xv.y * w1.y + xv.z * w2.y + xv.w * w3.y;
    vr.z = bv.z + xv.x * w0.z + xv.y * w1.z + xv.z * w2.z + xv.w * w3.z;
    vr.w = bv.w + xv.x * w0.w + xv.y * w1.w + xv.z * w2.w + xv.w * w3.w;
    uint2 p;
    p.x = rne_bf16(vl.x) | (rne_bf16(vl.y) << 16);
    p.y = rne_bf16(vl.z) | (rne_bf16(vl.w) << 16);
    xlh[n * 16 + cg] = p;
    uint2 r;
    r.x = rne_bf16(vr.x) | (rne_bf16(vr.y) << 16);
    r.y = rne_bf16(vr.z) | (rne_bf16(vr.w) << 16);
    xrh[n * 16 + cg] = r;
    if (cg == 0) deg[n] = 0;
}

// KA: direct-placement histogram (R15 win). v3: deg atomics demoted to
// workgroup scope -> execute in the OWNING XCD's L2 instead of the
// memory-side fabric (R16 falsified latency-bound; this attacks the
// device-scope atomic serialization directly). ovf_cnt stays device-scope.
__global__ __launch_bounds__(256) void ka_direct(const int* __restrict__ ei,
                                                 int* __restrict__ deg,
                                                 int* __restrict__ esrc,
                                                 int2* __restrict__ ovf,
                                                 int* __restrict__ ovf_cnt) {
    int xcd = blockIdx.x & 7;
    int sub = blockIdx.x >> 3;                 // 0..127
    int lo = xcd * (N_NODES / 8);
    int hi = lo + (N_NODES / 8);
    int tid = sub * 256 + (int)threadIdx.x;    // 0..32767 within XCD group
    for (int q = tid; q < N_EDGES / 4; q += 128 * 256) {
        int4 d4 = ((const int4*)(ei + N_EDGES))[q];
        int4 s4 = ((const int4*)ei)[q];
        int d[4] = {d4.x, d4.y, d4.z, d4.w};
        int s[4] = {s4.x, s4.y, s4.z, s4.w};
        int r[4];
        bool own[4];
#pragma unroll
        for (int k = 0; k < 4; ++k) {
            own[k] = (d[k] >= lo) && (d[k] < hi);
            r[k] = own[k] ? l2AtomicAdd(&deg[d[k]], 1) : 0;
        }
#pragma unroll
        for (int k = 0; k < 4; ++k) {
            if (own[k]) {
                if (r[k] < ECAP) {
                    esrc[d[k] * ECAP + r[k]] = s[k];
                } else {
                    int o = atomicAdd(ovf_cnt, 1);   // device scope (rare)
                    ovf[o] = make_int2(d[k], s[k]);
                }
            }
        }
    }
}

// KD: fused node aggregation + LN stats + graph pooling. SETTLED body
// (4 slots x 16 lanes, uint2, VGPR 32, 2048 blocks — R7/R9/R12/R13 lessons).
// Padded layout: base = n*ECAP, count = deg[n]; deg>ECAP scans overflow list.
__global__ __launch_bounds__(256, 8) void kd_node_agg(
    const int* __restrict__ deg, const int* __restrict__ esrc,
    const int2* __restrict__ ovf, const int* __restrict__ ovf_cnt,
    const uint2* __restrict__ xlh, const uint2* __restrict__ xrh,
    const float* __restrict__ att, const float* __restrict__ cb,
    const int* __restrict__ batch,
    float* __restrict__ gsum, float* __restrict__ gcnt,
    double* __restrict__ stats) {
    __shared__ float sS[4], sQ[4];
    int w = threadIdx.x >> 6;             // wave-in-block 0..3
    int lane = threadIdx.x & 63;
    int slot = lane >> 4;                 // 0..3: edge slot
    int cg = lane & 15;                   // channel group (4 ch)
    int wid = blockIdx.x * 4 + w;
    int n0 = wid * KD_CHUNK;
    int n1 = min(n0 + KD_CHUNK, N_NODES);

    float4 av = ((const float4*)att)[cg];
    float4 cv = ((const float4*)cb)[cg];

    float lsum = 0.f, lsq = 0.f;
    float gacc0 = 0.f, gacc1 = 0.f, gacc2 = 0.f, gacc3 = 0.f;
    float runcnt = 0.f;
    int cur_g = -1;

    for (int n = n0; n < n1; ++n) {
        int dtot = deg[n];
        int dpk = min(dtot, ECAP);
        int base = n * ECAP;
        uint2 rp = xrh[n * 16 + cg];
        float4 xr;
        xr.x = __uint_as_float(rp.x << 16);
        xr.y = __uint_as_float(rp.x & 0xffff0000u);
        xr.z = __uint_as_float(rp.y << 16);
        xr.w = __uint_as_float(rp.y & 0xffff0000u);
        float num0 = 0.f, num1 = 0.f, num2 = 0.f, num3 = 0.f, den = 0.f;
        int j = slot;
        uint2 p = make_uint2(0, 0);
        if (j < dpk) p = xlh[esrc[base + j] * 16 + cg];
        for (int j0 = 0; j0 < dpk; j0 += 4) {
            uint2 pc = p;
            bool vc = (j0 + slot) < dpk;
            int jn = j0 + 4 + slot;
            if (jn < dpk) p = xlh[esrc[base + jn] * 16 + cg];
            float f0 = __uint_as_float(pc.x << 16);
            float f1 = __uint_as_float(pc.x & 0xffff0000u);
            float f2 = __uint_as_float(pc.y << 16);
            float f3 = __uint_as_float(pc.y & 0xffff0000u);
            float h0 = f0 + xr.x, h1 = f1 + xr.y, h2 = f2 + xr.z, h3 = f3 + xr.w;
            float l0 = fmaxf(h0, 0.f) + 0.2f * fminf(h0, 0.f);
            float l1 = fmaxf(h1, 0.f) + 0.2f * fminf(h1, 0.f);
            float l2 = fmaxf(h2, 0.f) + 0.2f * fminf(h2, 0.f);
            float l3 = fmaxf(h3, 0.f) + 0.2f * fminf(h3, 0.f);
            float part = l0 * av.x + l1 * av.y + l2 * av.z + l3 * av.w;
            float e = groupReduceSum16(part);   // within-slot 16-lane reduce
            float ex = vc ? __expf(e) : 0.f;
            den += ex;
            num0 += ex * f0; num1 += ex * f1; num2 += ex * f2; num3 += ex * f3;
        }
        if (dtot > ECAP) {   // overflow fallback: scan tiny (dst,src) list
            int m = *ovf_cnt;
            for (int t = 0; t < m; ++t) {
                int2 od = ovf[t];
                if (od.x != n) continue;
                uint2 pc = make_uint2(0, 0);
                if (slot == 0) pc = xlh[od.y * 16 + cg];
                float f0 = __uint_as_float(pc.x << 16);
                float f1 = __uint_as_float(pc.x & 0xffff0000u);
                float f2 = __uint_as_float(pc.y << 16);
                float f3 = __uint_as_float(pc.y & 0xffff0000u);
                float h0 = f0 + xr.x, h1 = f1 + xr.y, h2 = f2 + xr.z, h3 = f3 + xr.w;
                float l0 = fmaxf(h0, 0.f) + 0.2f * fminf(h0, 0.f);
                float l1 = fmaxf(h1, 0.f) + 0.2f * fminf(h1, 0.f);
                float l2 = fmaxf(h2, 0.f) + 0.2f * fminf(h2, 0.f);
                float l3 = fmaxf(h3, 0.f) + 0.2f * fminf(h3, 0.f);
                float part = l0 * av.x + l1 * av.y + l2 * av.z + l3 * av.w;
                float e = groupReduceSum16(part);
                float ex = (slot == 0) ? __expf(e) : 0.f;
                den += ex;
                num0 += ex * f0; num1 += ex * f1; num2 += ex * f2; num3 += ex * f3;
            }
        }
#pragma unroll
        for (int off = 16; off <= 32; off <<= 1) {
            num0 += __shfl_xor(num0, off, 64);
            num1 += __shfl_xor(num1, off, 64);
            num2 += __shfl_xor(num2, off, 64);
            num3 += __shfl_xor(num3, off, 64);
            den += __shfl_xor(den, off, 64);
        }
        float inv = (den > 0.f) ? (1.f / den) : 0.f;
        float v0 = fmaxf(num0 * inv + cv.x, 0.f);
        float v1 = fmaxf(num1 * inv + cv.y, 0.f);
        float v2 = fmaxf(num2 * inv + cv.z, 0.f);
        float v3 = fmaxf(num3 * inv + cv.w, 0.f);
        if (slot == 0) {   // values replicated across slots; count once
            lsum += v0 + v1 + v2 + v3;
            lsq += v0 * v0 + v1 * v1 + v2 * v2 + v3 * v3;
            int g = batch[n];
            if (g != cur_g) {
                if (cur_g >= 0) {
                    unsafeAtomicAdd(&gsum[cur_g * HID + cg * 4 + 0], gacc0);
                    unsafeAtomicAdd(&gsum[cur_g * HID + cg * 4 + 1], gacc1);
                    unsafeAtomicAdd(&gsum[cur_g * HID + cg * 4 + 2], gacc2);
                    unsafeAtomicAdd(&gsum[cur_g * HID + cg * 4 + 3], gacc3);
                    if (cg == 0) unsafeAtomicAdd(&gcnt[cur_g], runcnt);
                }
                cur_g = g;
                gacc0 = gacc1 = gacc2 = gacc3 = 0.f;
                runcnt = 0.f;
            }
            gacc0 += v0; gacc1 += v1; gacc2 += v2; gacc3 += v3;
            runcnt += 1.f;
        }
    }
    if (cur_g >= 0) {   // only slot-0 lanes have cur_g >= 0
        unsafeAtomicAdd(&gsum[cur_g * HID + cg * 4 + 0], gacc0);
        unsafeAtomicAdd(&gsum[cur_g * HID + cg * 4 + 1], gacc1);
        unsafeAtomicAdd(&gsum[cur_g * HID + cg * 4 + 2], gacc2);
        unsafeAtomicAdd(&gsum[cur_g * HID + cg * 4 + 3], gacc3);
        if (cg == 0) unsafeAtomicAdd(&gcnt[cur_g], runcnt);
    }
    lsum = groupReduceSum16(lsum);
    lsq = groupReduceSum16(lsq);
    if (lane == 0) { sS[w] = lsum; sQ[w] = lsq; }
    __syncthreads();
    if (threadIdx.x == 0) {
        double ds = 0.0, dq = 0.0;
#pragma unroll
        for (int i = 0; i < 4; ++i) { ds += (double)sS[i]; dq += (double)sQ[i]; }
        unsafeAtomicAdd(&stats[0], ds);
        unsafeAtomicAdd(&stats[1], dq);
    }
}

// K4: per-graph head (separate launch; fence fusion costs 135us — R12).
__global__ __launch_bounds__(64) void k4_head(
    const float* __restrict__ gsum, const float* __restrict__ gcnt,
    const double* __restrict__ stats,
    const float* __restrict__ lnw, const float* __restrict__ lnb,
    const float* __restrict__ linw, const float* __restrict__ linb,
    float* __restrict__ y) {
    int g = blockIdx.x;
    int lane = threadIdx.x;
    double tot = (double)N_NODES * (double)HID;
    double mu = stats[0] / tot;
    double var = stats[1] / tot - mu * mu;
    float rs = rsqrtf((float)var + LN_EPS);
    float cnt = fmaxf(gcnt[g], 1.f);
    float pooled = (gsum[g * HID + lane] / cnt - (float)mu) * rs * lnw[lane] + lnb[lane];
    float t = waveReduceSum(pooled * linw[lane]);
    if (lane == 0) {
        float z = t + linb[0];
        y[g] = 1.f / (1.f + __expf(-z));
    }
}

extern "C" void kernel_launch(void* const* d_in, const int* in_sizes, int n_in,
                              void* d_out, int out_size, void* d_ws, size_t ws_size,
                              hipStream_t stream) {
    const float* x = (const float*)d_in[0];
    const int* ei = (const int*)d_in[1];
    const int* batch = (const int*)d_in[2];
    const float* Wl = (const float*)d_in[3];
    const float* bl = (const float*)d_in[4];
    const float* Wr = (const float*)d_in[5];
    const float* br = (const float*)d_in[6];
    const float* att = (const float*)d_in[7];
    const float* cb = (const float*)d_in[8];
    const float* lnw = (const float*)d_in[9];
    const float* lnb = (const float*)d_in[10];
    const float* linw = (const float*)d_in[11];
    const float* linb = (const float*)d_in[12];
    float* y = (float*)d_out;

    char* ws = (char*)d_ws;
    uint2* xlh = (uint2*)ws;                                     // N*16 uint2 (12.8MB)
    uint2* xrh = (uint2*)(ws + (size_t)N_NODES * 128);           // N*16 uint2 (12.8MB)
    float* gsum = (float*)(ws + (size_t)N_NODES * 256);          // 64*64
    float* gcnt = gsum + N_GRAPHS * HID;                         // 64
    double* stats = (double*)(gcnt + N_GRAPHS);                  // 2 doubles
    int* deg = (int*)(stats + 2);                                // N
    int* ovf_cnt = deg + N_NODES;                                // 1 (+1 pad)
    int2* ovf = (int2*)(ovf_cnt + 2);                            // OVF_CAP int2
    int* esrc = (int*)(ovf + OVF_CAP);                           // N*ECAP (12.8MB)

    k0_transform<<<(N_NODES * 16 + 255) / 256, 256, 0, stream>>>(
        x, Wl, bl, Wr, br, xlh, xrh, deg, ovf_cnt, gsum, gcnt, stats);
    ka_direct<<<KA_BLOCKS, 256, 0, stream>>>(ei, deg, esrc, ovf, ovf_cnt);
    kd_node_agg<<<KD_BLOCKS, 256, 0, stream>>>(
        deg, esrc, ovf, ovf_cnt, xlh, xrh, att, cb, batch, gsum, gcnt, stats);
    k4_head<<<N_GRAPHS, 64, 0, stream>>>(gsum, gcnt, stats, lnw, lnb, linw, linb, y);
}